// Round 2
// baseline (266.045 us; speedup 1.0000x reference)
//
#include <hip/hip_runtime.h>
#include <stdint.h>

// ---------------------------------------------------------------------------
// Self-attention, B=4 S=2048 D=1024, fp32 in/out, fp16 MFMA compute.
//   0) cvt: x -> xh fp16; w_q/w_k/w_v -> wh fp16 (one dispatch)
//   1) proj z=3: z<2 -> q,k fp16 row-major; z==2 -> vt[b][d][s] (LDS transp.)
//   2) scores = q_b @ k_b^T -> fp16 (z=batch)
//   3) softmax rows in place fp16->fp16
//   4) out_b = attn_b @ vt_b^T (fp32)
// R8: 256x256 tile, BK=64, 4 phases per K-tile (m201 quadrant: 16 MFMA per
// phase), counted vmcnt, s_setprio around MFMA clusters. 8 waves 2Mx4N with
// INTERLEAVED half ownership: wave rows = mh*128 + wr*64 + [0,64),
// cols = nh*128 + wc*32 + [0,32) -> phase (mh,nh) reads exactly A-half mh +
// B-half nh. Phase order A1B0, A0B0, A1B1, A0B1; phase i stages half Hi of
// tile t+1 (H1=A1,H2=B0,H3=A0,H4=B1) into the OTHER 64KB buffer (fully dead
// since end of tile t-1). Waits: vmcnt(4) at end of P1/P2/P4 -> the needed
// half is always staged >=2 phases before its wait, and the 2 newest halves
// stay in flight (never drains). Boundary tile: vmcnt(2)/vmcnt(0).
// LDS 2 x 64KB = 128KB -> 1 block/CU. 24 ds_read_b128 per K-tile per wave
// (minimum: af 2-banked, bf 1-banked). XOR chunk swizzle, bm-fastest grid.
// ---------------------------------------------------------------------------

typedef __attribute__((ext_vector_type(8))) _Float16 f16x8;
typedef __attribute__((ext_vector_type(4))) float f32x4;
typedef __attribute__((ext_vector_type(4))) unsigned short u16x4;

__device__ inline unsigned short f2h(float f) {
    union { _Float16 h; unsigned short u; } x;
    x.h = (_Float16)f;   // RNE
    return x.u;
}
__device__ inline float h2f(unsigned short u) {
    union { unsigned short u; _Float16 h; } x;
    x.u = u;
    return (float)x.h;
}

__device__ inline void async16(const unsigned short* g, unsigned short* l) {
    __builtin_amdgcn_global_load_lds(
        (__attribute__((address_space(1))) void*)g,
        (__attribute__((address_space(3))) void*)l, 16, 0, 0);
}

// LDS layout per 32768-half buffer: A0 @0, A1 @8192, B0 @16384, B1 @24576.
// Staging: 16B chunk l (thread t stages l = t, t+512 per half): row r=l>>3
// within the 128-row half, phys slot l&7 holds logical k-chunk (l&7)^(r&7).
// MODE 0: proj: z<2 -> fp16 row-major into C (+z*sCz); z==2 -> vt transpose
//         into C2 (vt[b][d][s], ld 2048, batch stride 2^21).
// MODE 1: fp16 row-major into C (scores).  MODE 2: fp32 row-major (out).
template <int MODE>
__global__ __launch_bounds__(512)
void gemm256(const unsigned short* __restrict__ A,
             const unsigned short* __restrict__ B,
             void* __restrict__ C, void* __restrict__ C2,
             int K, int ldA, int ldB, int ldC,
             long sAz, long sBz, long sCz)
{
    __shared__ __align__(16) unsigned short smem[65536];   // 128 KB

    const int tid  = threadIdx.x;
    const int lane = tid & 63;
    const int wave = tid >> 6;
    const int wr   = wave >> 2;        // 0..1: 64-row band within each 128-half
    const int wc   = wave & 3;         // 0..3: 32-col slice within each 128-half
    const int quad = lane >> 4, lrow = lane & 15;
    const int bm = blockIdx.x, bn = blockIdx.y, z = blockIdx.z;  // bm fastest

    const unsigned short* Az = A + (long)z * sAz;
    const unsigned short* Bz = B + (long)z * sBz;

    // staging pointers: gA[h][i] -> A rows bm*256 + h*128 + r
    const unsigned short* gA[2][2];
    const unsigned short* gB[2][2];
#pragma unroll
    for (int h = 0; h < 2; ++h)
#pragma unroll
        for (int i = 0; i < 2; ++i) {
            const int l = tid + 512 * i;
            const int r = l >> 3;
            const int c = (l & 7) ^ (r & 7);
            gA[h][i] = Az + (long)(bm * 256 + h * 128 + r) * ldA + c * 8;
            gB[h][i] = Bz + (long)(bn * 256 + h * 128 + r) * ldB + c * 8;
        }

    f32x4 acc[2][2][4][2];
#pragma unroll
    for (int a = 0; a < 2; ++a)
#pragma unroll
        for (int b = 0; b < 2; ++b)
#pragma unroll
            for (int m = 0; m < 4; ++m)
#pragma unroll
                for (int n = 0; n < 2; ++n)
                    acc[a][b][m][n] = f32x4{0.f, 0.f, 0.f, 0.f};

    const int fr  = lrow & 7;               // row bits for de-swizzle
    const int pc0 = (quad ^ fr) * 8;        // ks=0 chunk
    const int pc1 = ((4 + quad) ^ fr) * 8;  // ks=1 chunk
    const int ntiles = K >> 6;

    // ---- prologue: tile0 halves, issue order H1=A1,H2=B0,H3=A0,H4=B1 ----
    async16(gA[1][0], smem + 8192 + tid * 8);
    async16(gA[1][1], smem + 8192 + (tid + 512) * 8);
    async16(gB[0][0], smem + 16384 + tid * 8);
    async16(gB[0][1], smem + 16384 + (tid + 512) * 8);
    async16(gA[0][0], smem + tid * 8);
    async16(gA[0][1], smem + (tid + 512) * 8);
    async16(gB[1][0], smem + 24576 + tid * 8);
    async16(gB[1][1], smem + 24576 + (tid + 512) * 8);
#pragma unroll
    for (int h = 0; h < 2; ++h)
#pragma unroll
        for (int i = 0; i < 2; ++i) { gA[h][i] += 64; gB[h][i] += 64; }

    asm volatile("s_waitcnt vmcnt(4)" ::: "memory");
    __builtin_amdgcn_s_barrier();

    f16x8 af[2][4][2], bf[2][2];

    for (int t = 0; t < ntiles; ++t) {
        const unsigned short* sb = smem + (t & 1) * 32768;
        unsigned short*       nb = smem + ((t + 1) & 1) * 32768;
        const bool pf = (t + 1 < ntiles);

        // ---- P1: quadrant (mh1,nh0); reads A1,B0; stages A1(t+1) ----
#pragma unroll
        for (int mt = 0; mt < 4; ++mt) {
            const int ro = 8192 + (wr * 64 + mt * 16 + lrow) * 64;
            af[1][mt][0] = *(const f16x8*)&sb[ro + pc0];
            af[1][mt][1] = *(const f16x8*)&sb[ro + pc1];
        }
#pragma unroll
        for (int n = 0; n < 2; ++n) {
            const int ro = 16384 + (wc * 32 + n * 16 + lrow) * 64;
            bf[n][0] = *(const f16x8*)&sb[ro + pc0];
            bf[n][1] = *(const f16x8*)&sb[ro + pc1];
        }
        if (pf) {
            async16(gA[1][0], nb + 8192 + tid * 8);
            async16(gA[1][1], nb + 8192 + (tid + 512) * 8);
            gA[1][0] += 64; gA[1][1] += 64;
        }
        __builtin_amdgcn_s_barrier();
        asm volatile("s_waitcnt lgkmcnt(0)");
        __builtin_amdgcn_s_setprio(1);
#pragma unroll
        for (int mt = 0; mt < 4; ++mt)
#pragma unroll
            for (int n = 0; n < 2; ++n)
#pragma unroll
                for (int ks = 0; ks < 2; ++ks)
                    acc[1][0][mt][n] = __builtin_amdgcn_mfma_f32_16x16x32_f16(
                        af[1][mt][ks], bf[n][ks], acc[1][0][mt][n], 0, 0, 0);
        __builtin_amdgcn_s_setprio(0);
        if (pf) asm volatile("s_waitcnt vmcnt(4)" ::: "memory");
        else    asm volatile("s_waitcnt vmcnt(2)" ::: "memory");
        __builtin_amdgcn_s_barrier();

        // ---- P2: (mh0,nh0); reads A0 (bf reused); stages B0(t+1) ----
#pragma unroll
        for (int mt = 0; mt < 4; ++mt) {
            const int ro = (wr * 64 + mt * 16 + lrow) * 64;
            af[0][mt][0] = *(const f16x8*)&sb[ro + pc0];
            af[0][mt][1] = *(const f16x8*)&sb[ro + pc1];
        }
        if (pf) {
            async16(gB[0][0], nb + 16384 + tid * 8);
            async16(gB[0][1], nb + 16384 + (tid + 512) * 8);
            gB[0][0] += 64; gB[0][1] += 64;
        }
        __builtin_amdgcn_s_barrier();
        asm volatile("s_waitcnt lgkmcnt(0)");
        __builtin_amdgcn_s_setprio(1);
#pragma unroll
        for (int mt = 0; mt < 4; ++mt)
#pragma unroll
            for (int n = 0; n < 2; ++n)
#pragma unroll
                for (int ks = 0; ks < 2; ++ks)
                    acc[0][0][mt][n] = __builtin_amdgcn_mfma_f32_16x16x32_f16(
                        af[0][mt][ks], bf[n][ks], acc[0][0][mt][n], 0, 0, 0);
        __builtin_amdgcn_s_setprio(0);
        if (pf) asm volatile("s_waitcnt vmcnt(4)" ::: "memory");
        else    asm volatile("s_waitcnt vmcnt(0)" ::: "memory");
        __builtin_amdgcn_s_barrier();

        // ---- P3: (mh1,nh1); reads B1 (af[1] reused); stages A0(t+1) ----
#pragma unroll
        for (int n = 0; n < 2; ++n) {
            const int ro = 24576 + (wc * 32 + n * 16 + lrow) * 64;
            bf[n][0] = *(const f16x8*)&sb[ro + pc0];
            bf[n][1] = *(const f16x8*)&sb[ro + pc1];
        }
        if (pf) {
            async16(gA[0][0], nb + tid * 8);
            async16(gA[0][1], nb + (tid + 512) * 8);
            gA[0][0] += 64; gA[0][1] += 64;
        }
        __builtin_amdgcn_s_barrier();
        asm volatile("s_waitcnt lgkmcnt(0)");
        __builtin_amdgcn_s_setprio(1);
#pragma unroll
        for (int mt = 0; mt < 4; ++mt)
#pragma unroll
            for (int n = 0; n < 2; ++n)
#pragma unroll
                for (int ks = 0; ks < 2; ++ks)
                    acc[1][1][mt][n] = __builtin_amdgcn_mfma_f32_16x16x32_f16(
                        af[1][mt][ks], bf[n][ks], acc[1][1][mt][n], 0, 0, 0);
        __builtin_amdgcn_s_setprio(0);
        __builtin_amdgcn_s_barrier();

        // ---- P4: (mh0,nh1); no reads (af[0],bf reused); stages B1(t+1) ----
        if (pf) {
            async16(gB[1][0], nb + 24576 + tid * 8);
            async16(gB[1][1], nb + 24576 + (tid + 512) * 8);
            gB[1][0] += 64; gB[1][1] += 64;
        }
        __builtin_amdgcn_s_setprio(1);
#pragma unroll
        for (int mt = 0; mt < 4; ++mt)
#pragma unroll
            for (int n = 0; n < 2; ++n)
#pragma unroll
                for (int ks = 0; ks < 2; ++ks)
                    acc[0][1][mt][n] = __builtin_amdgcn_mfma_f32_16x16x32_f16(
                        af[0][mt][ks], bf[n][ks], acc[0][1][mt][n], 0, 0, 0);
        __builtin_amdgcn_s_setprio(0);
        if (pf) asm volatile("s_waitcnt vmcnt(4)" ::: "memory");
        __builtin_amdgcn_s_barrier();
    }

    if (MODE != 0 || z < 2) {
        const long zC = (long)z * sCz;
#pragma unroll
        for (int mh = 0; mh < 2; ++mh)
#pragma unroll
            for (int nh = 0; nh < 2; ++nh)
#pragma unroll
                for (int mt = 0; mt < 4; ++mt)
#pragma unroll
                    for (int n = 0; n < 2; ++n)
#pragma unroll
                        for (int r = 0; r < 4; ++r) {
                            const int row = bm * 256 + mh * 128 + wr * 64 +
                                            mt * 16 + quad * 4 + r;
                            const int col = bn * 256 + nh * 128 + wc * 32 +
                                            n * 16 + lrow;
                            if (MODE == 2)
                                ((float*)C)[zC + (long)row * ldC + col] =
                                    acc[mh][nh][mt][n][r];
                            else
                                ((unsigned short*)C)[zC + (long)row * ldC + col] =
                                    f2h(acc[mh][nh][mt][n][r]);
                        }
    } else {
        // vt transpose: 4 bands of 64 token-rows; band p -> (mh=p>>1, wr=p&1).
        // T[col 256][row 64] pitch 72 halves (16B-aligned rows); aliases smem
        // (fully dead: final tile drained vmcnt(0) at P2, all waves past loop).
        unsigned short* T = smem;   // 256*72 = 18432 halves <= 65536
#pragma unroll
        for (int p = 0; p < 4; ++p) {
            __syncthreads();
            if (wr == (p & 1)) {
                const int mh = p >> 1;
#pragma unroll
                for (int mt = 0; mt < 4; ++mt)
#pragma unroll
                    for (int nh = 0; nh < 2; ++nh)
#pragma unroll
                        for (int n = 0; n < 2; ++n) {
                            const int row_l = mt * 16 + quad * 4;
                            const int col_l = nh * 128 + wc * 32 + n * 16 + lrow;
                            u16x4 pk = {f2h(acc[mh][nh][mt][n][0]),
                                        f2h(acc[mh][nh][mt][n][1]),
                                        f2h(acc[mh][nh][mt][n][2]),
                                        f2h(acc[mh][nh][mt][n][3])};
                            *(u16x4*)&T[col_l * 72 + row_l] = pk;
                        }
            }
            __syncthreads();
            // copy out: 256 cols x 64 rows = 16384 halves = 512 thr x 32
            const int c  = tid >> 1;
            const int j0 = (tid & 1) * 32;
            const int tok0 = bm * 256 + p * 64;   // tile never crosses a batch
            const int bb = tok0 >> 11;            // (2048 % 256 == 0)
            const int s0 = (tok0 & 2047) + j0;
            unsigned short* dst = (unsigned short*)C2 + (long)bb * 2097152 +
                                  (long)(bn * 256 + c) * 2048 + s0;
            const unsigned short* srcT = &T[c * 72 + j0];
            *(f16x8*)dst        = *(const f16x8*)srcT;
            *(f16x8*)(dst + 8)  = *(const f16x8*)(srcT + 8);
            *(f16x8*)(dst + 16) = *(const f16x8*)(srcT + 16);
            *(f16x8*)(dst + 24) = *(const f16x8*)(srcT + 24);
        }
    }
}

// fused fp32 -> fp16 conversion: blocks [0,4096) -> x, [4096,5632) -> weights
__global__ __launch_bounds__(256)
void cvt_all(const float* __restrict__ x, const float* __restrict__ w0,
             const float* __restrict__ w1, const float* __restrict__ w2,
             unsigned short* __restrict__ xh, unsigned short* __restrict__ wh)
{
    const int bid = blockIdx.x;
    const float* s;
    unsigned short* d;
    long i;
    if (bid < 4096) {
        s = x; d = xh;
        i = ((long)bid * 256 + threadIdx.x) * 8;
    } else {
        const int wid = bid - 4096;          // [0,1536)
        const int w = wid >> 9;              // weight index
        s = (w == 0) ? w0 : (w == 1) ? w1 : w2;
        d = wh + (long)w * 1048576;
        i = ((long)(wid & 511) * 256 + threadIdx.x) * 8;
    }
    f32x4 a = *(const f32x4*)(s + i);
    f32x4 b = *(const f32x4*)(s + i + 4);
    union { unsigned short u[8]; f16x8 v; } t;
#pragma unroll
    for (int j = 0; j < 4; ++j) { t.u[j] = f2h(a[j]); t.u[4 + j] = f2h(b[j]); }
    *(f16x8*)(d + i) = t.v;
}

// in-place fp16 row softmax: row = 2048 fp16, one block per row.
__global__ __launch_bounds__(256)
void softmax16(unsigned short* __restrict__ sc)
{
    const long row = blockIdx.x;
    unsigned short* srow = sc + row * 2048;
    const int tid = threadIdx.x;

    union { u16x4 p[2]; unsigned short u[8]; } in;
    in.p[0] = *(const u16x4*)(srow + tid * 8);
    in.p[1] = *(const u16x4*)(srow + tid * 8 + 4);
    float v[8];
#pragma unroll
    for (int i = 0; i < 8; ++i) v[i] = h2f(in.u[i]);

    float m = v[0];
#pragma unroll
    for (int i = 1; i < 8; ++i) m = fmaxf(m, v[i]);
#pragma unroll
    for (int off = 32; off; off >>= 1) m = fmaxf(m, __shfl_xor(m, off));

    __shared__ float redm[4], reds[4];
    if ((tid & 63) == 0) redm[tid >> 6] = m;
    __syncthreads();
    m = fmaxf(fmaxf(redm[0], redm[1]), fmaxf(redm[2], redm[3]));

    float s = 0.f;
#pragma unroll
    for (int i = 0; i < 8; ++i) { v[i] = __expf(v[i] - m); s += v[i]; }
#pragma unroll
    for (int off = 32; off; off >>= 1) s += __shfl_xor(s, off);
    if ((tid & 63) == 0) reds[tid >> 6] = s;
    __syncthreads();
    s = reds[0] + reds[1] + reds[2] + reds[3];

    const float inv = 1.f / s;
    union { unsigned short u[8]; f16x8 w; } t;
#pragma unroll
    for (int i = 0; i < 8; ++i) t.u[i] = f2h(v[i] * inv);
    *(f16x8*)(srow + tid * 8) = t.w;
}

extern "C" void kernel_launch(void* const* d_in, const int* in_sizes, int n_in,
                              void* d_out, int out_size, void* d_ws, size_t ws_size,
                              hipStream_t stream)
{
    const float* x  = (const float*)d_in[0];
    const float* wq = (const float*)d_in[1];
    const float* wk = (const float*)d_in[2];
    const float* wv = (const float*)d_in[3];
    float* out = (float*)d_out;

    // batched: [sc fp16 33.5MB (aliases xh 16.8 | wh 6.3)] [q][k][vt] = 83.9MB
    // looped:  [xh|wh 23.1MB (per-batch sc fp16 8.4MB aliases xh)][q][k][vt]
    //          = 73.4MB
    char* base = (char*)d_ws;
    const bool batched = (ws_size >= 88080384UL);   // 84 MB

    unsigned short* xh = (unsigned short*)base;
    unsigned short* wh = (unsigned short*)(base + 16777216);
    unsigned short* sc = (unsigned short*)base;
    unsigned short* q  = (unsigned short*)(base + (batched ? 33554432 : 23068672));
    unsigned short* k  = q + 8388608;
    unsigned short* vt = k + 8388608;

    // 0) conversions (single dispatch)
    cvt_all<<<5632, 256, 0, stream>>>(x, wq, wk, wv, xh, wh);

    // 1) fused projections: M=8192 N=1024 K=1024; z=0,1 -> q,k; z=2 -> vt
    //    grid (32,4,3) = 384 blocks (1.5 rounds at 1 block/CU)
    gemm256<0><<<dim3(32, 4, 3), 512, 0, stream>>>(
        xh, wh, q, vt, 1024, 1024, 1024, 1024, 0L, 1048576L, 8388608L);

    if (batched) {
        // 2) scores fp16: M=N=2048 K=1024, z=batch; (8,8,4)=256 = 1 round
        gemm256<1><<<dim3(8, 8, 4), 512, 0, stream>>>(
            q, k, sc, nullptr, 1024, 1024, 1024, 2048,
            2097152L, 2097152L, 4194304L);
        // 3) softmax in place (8192 rows, fp16->fp16)
        softmax16<<<8192, 256, 0, stream>>>(sc);
        // 4) out: M=2048 N=1024 K=2048; (8,4,4)=128 blocks (half round, but
        //    per-block wall time beats the old 512-block BN=64 shape)
        gemm256<2><<<dim3(8, 4, 4), 512, 0, stream>>>(
            sc, vt, out, nullptr, 2048, 2048, 2048, 1024,
            4194304L, 2097152L, 2097152L);
    } else {
        for (int b = 0; b < 4; ++b) {
            gemm256<1><<<dim3(8, 8, 1), 512, 0, stream>>>(
                q + (long)b * 2097152, k + (long)b * 2097152, sc, nullptr,
                1024, 1024, 1024, 2048, 0L, 0L, 0L);
            softmax16<<<2048, 256, 0, stream>>>(sc);
            gemm256<2><<<dim3(8, 4, 1), 512, 0, stream>>>(
                sc, vt + (long)b * 2097152, out + (long)b * 2097152, nullptr,
                2048, 2048, 2048, 1024, 0L, 0L, 0L);
        }
    }
}

// Round 3
// 224.558 us; speedup vs baseline: 1.1847x; 1.1847x over previous
//
#include <hip/hip_runtime.h>
#include <hip/hip_bf16.h>
#include <stdint.h>

// ---------------------------------------------------------------------------
// Self-attention, B=4 S=2048 D=1024, fp32 in/out, fp16 MFMA compute.
//   0) cvt: x -> xh fp16; w_q/w_k/w_v -> wh fp16 (one dispatch)
//   1) proj z=3: z<2 -> q,k fp16 row-major; z==2 -> vt[b][d][s] (LDS transp.)
//   2) scores = q_b @ k_b^T -> fp16 (z=batch)
//   3) softmax rows in place fp16->fp16
//   4) out_b = attn_b @ vt_b^T (fp32) -- R9: double-buffered 2-phase gemm_out
// GEMM (proj/scores): 512 threads, 256xBN tile, BK=64, 8 waves (4x2), MFMA
// 16x16x32_f16, 48 KB LDS, 3 blocks/CU; serial stage->drain->compute (best
// measured structure for this K: R7/R8 showed 1-block/CU pipelines lose).
// gemm_out (R9): BN=64, 2x40KB double-buffer (80KB -> 2 blocks/CU, equal to
// its 512-block residency), stage(t+1) issued BEFORE compute(t), single
// __syncthreads per K-tile (implicit vmcnt(0) drain covered by compute).
// ---------------------------------------------------------------------------

typedef __attribute__((ext_vector_type(8))) _Float16 f16x8;
typedef __attribute__((ext_vector_type(4))) float f32x4;
typedef __attribute__((ext_vector_type(4))) unsigned short u16x4;

__device__ inline unsigned short f2h(float f) {
    union { _Float16 h; unsigned short u; } x;
    x.h = (_Float16)f;   // RNE
    return x.u;
}
__device__ inline float h2f(unsigned short u) {
    union { unsigned short u; _Float16 h; } x;
    x.u = u;
    return (float)x.h;
}

__device__ inline void async16(const unsigned short* g, unsigned short* l) {
    __builtin_amdgcn_global_load_lds(
        (__attribute__((address_space(1))) void*)g,
        (__attribute__((address_space(3))) void*)l, 16, 0, 0);
}

// MODE 0: proj (BN=128): z<2 -> fp16 row-major into C (+z*sCz);
//         z==2 -> vt transpose into C2 (vt[b][d][s], ld 2048, bstride 2^21).
// MODE 1: fp16 row-major into C (scores).
// Tile: BM=256 rows x BN cols, BK=64. 8 waves: wr=wave>>1 (4), wc=wave&1 (2).
template <int MODE, int BN>
__global__ __launch_bounds__(512)
void gemm512(const unsigned short* __restrict__ A,
             const unsigned short* __restrict__ B,
             void* __restrict__ C, void* __restrict__ C2,
             int K, int ldA, int ldB, int ldC,
             long sAz, long sBz, long sCz)
{
    constexpr int NT = BN / 32;           // MFMA col-tiles per wave
    constexpr int BI = BN / 64;           // B staging chunks per thread
    __shared__ __align__(16) unsigned short smem[256 * 64 + BN * 64];
    unsigned short* As = smem;
    unsigned short* Bs = smem + 256 * 64;

    const int tid  = threadIdx.x;
    const int lane = tid & 63;
    const int wave = tid >> 6;
    const int wr   = wave >> 1, wc = wave & 1;
    const int quad = lane >> 4, lrow = lane & 15;
    const int bm   = blockIdx.x, bn = blockIdx.y, z = blockIdx.z;  // bm fastest

    const unsigned short* Az = A + (long)z * sAz;
    const unsigned short* Bz = B + (long)z * sBz;

    // staging: 16B chunks; chunk l -> row l>>3, phys slot l&7, holding logical
    // k-chunk (l&7)^(row&7) (XOR swizzle). Thread t stages l = t + 512*i.
    const unsigned short* gA[4];
    const unsigned short* gB[BI];
#pragma unroll
    for (int i = 0; i < 4; ++i) {
        const int l = tid + 512 * i;
        const int r = l >> 3;
        const int c = (l & 7) ^ (r & 7);
        gA[i] = Az + (long)(bm * 256 + r) * ldA + c * 8;
    }
#pragma unroll
    for (int i = 0; i < BI; ++i) {
        const int l = tid + 512 * i;
        const int r = l >> 3;
        const int c = (l & 7) ^ (r & 7);
        gB[i] = Bz + (long)(bn * BN + r) * ldB + c * 8;
    }

    f32x4 acc[4][NT];
#pragma unroll
    for (int i = 0; i < 4; ++i)
#pragma unroll
        for (int j = 0; j < NT; ++j)
            acc[i][j] = f32x4{0.f, 0.f, 0.f, 0.f};

    const int fr = lrow & 7;   // row bits for fragment de-swizzle

    for (int k0 = 0; k0 < K; k0 += 64) {
#pragma unroll
        for (int i = 0; i < 4; ++i) async16(gA[i], &As[(tid + 512 * i) * 8]);
#pragma unroll
        for (int i = 0; i < BI; ++i) async16(gB[i], &Bs[(tid + 512 * i) * 8]);
#pragma unroll
        for (int i = 0; i < 4; ++i) gA[i] += 64;
#pragma unroll
        for (int i = 0; i < BI; ++i) gB[i] += 64;
        __syncthreads();   // drains vmcnt -> tiles visible

#pragma unroll
        for (int ks = 0; ks < 2; ++ks) {
            const int pc = (((ks << 2) + quad) ^ fr) * 8;
            f16x8 af[4], bf[NT];
#pragma unroll
            for (int mt = 0; mt < 4; ++mt)
                af[mt] = *(const f16x8*)&As[(wr * 64 + mt * 16 + lrow) * 64 + pc];
#pragma unroll
            for (int nt = 0; nt < NT; ++nt)
                bf[nt] = *(const f16x8*)&Bs[(wc * (BN / 2) + nt * 16 + lrow) * 64 + pc];
#pragma unroll
            for (int mt = 0; mt < 4; ++mt)
#pragma unroll
                for (int nt = 0; nt < NT; ++nt)
                    acc[mt][nt] = __builtin_amdgcn_mfma_f32_16x16x32_f16(
                        af[mt], bf[nt], acc[mt][nt], 0, 0, 0);
        }
        __syncthreads();   // LDS reusable
    }

    const int col_base = bn * BN + wc * (BN / 2);

    if (MODE != 0 || z < 2) {
        const int row_base = bm * 256 + wr * 64;
        const long zC = (long)z * sCz;
#pragma unroll
        for (int mt = 0; mt < 4; ++mt)
#pragma unroll
            for (int nt = 0; nt < NT; ++nt)
#pragma unroll
                for (int r = 0; r < 4; ++r) {
                    const int row = row_base + mt * 16 + quad * 4 + r;
                    const int col = col_base + nt * 16 + lrow;
                    if (MODE == 2)
                        ((float*)C)[zC + (long)row * ldC + col] = acc[mt][nt][r];
                    else
                        ((unsigned short*)C)[zC + (long)row * ldC + col] =
                            f2h(acc[mt][nt][r]);
                }
    } else {
        // vt transpose (BN=128): 4 phases of 64 token-rows. T[col 128][row 64]
        // pitch 72 halves (144B rows keep 16B align); aliases As (post-barrier).
        unsigned short* T = smem;   // 128*72 = 9216 halves <= 16384
#pragma unroll
        for (int p = 0; p < 4; ++p) {
            __syncthreads();
            if (wr == p) {
#pragma unroll
                for (int mt = 0; mt < 4; ++mt)
#pragma unroll
                    for (int nt = 0; nt < NT; ++nt) {
                        const int row_l = mt * 16 + quad * 4;     // within band
                        const int col_l = wc * 64 + nt * 16 + lrow;
                        u16x4 pk = {f2h(acc[mt][nt][0]), f2h(acc[mt][nt][1]),
                                    f2h(acc[mt][nt][2]), f2h(acc[mt][nt][3])};
                        *(u16x4*)&T[col_l * 72 + row_l] = pk;
                    }
            }
            __syncthreads();
            // copy out: 128 cols x 64 rows = 8192 halves = 512 thr x 16
            const int c  = tid >> 2;
            const int j0 = (tid & 3) * 16;
            const int tok0 = bm * 256 + p * 64;   // 256-row tile never crosses
            const int bb = tok0 >> 11;            // a batch boundary (2048%256=0)
            const int s0 = (tok0 & 2047) + j0;
            unsigned short* dst = (unsigned short*)C2 + (long)bb * 2097152 +
                                  (long)(bn * 128 + c) * 2048 + s0;
            const unsigned short* srcT = &T[c * 72 + j0];
            *(f16x8*)dst = *(const f16x8*)srcT;
            *(f16x8*)(dst + 8) = *(const f16x8*)(srcT + 8);
        }
    }
}

// R9: out GEMM. BM=256 x BN=64, BK=64, fp32 row-major C. Double-buffered
// 2-phase: stage(t+1) issued BEFORE compute(t); ONE __syncthreads per K-tile
// (its implicit vmcnt(0) drains loads that flew under ~300 cy of compute).
// LDS 2 x (256+64)*64*2B = 80 KB -> 2 blocks/CU (matches 512-block grid).
__global__ __launch_bounds__(512)
void gemm_out(const unsigned short* __restrict__ A,
              const unsigned short* __restrict__ B,
              float* __restrict__ C,
              int K, int ldA, int ldB, int ldC,
              long sAz, long sBz, long sCz)
{
    constexpr int TILE_H = 256 * 64 + 64 * 64;   // 20480 halves = 40 KB
    __shared__ __align__(16) unsigned short smem[2 * TILE_H];

    const int tid  = threadIdx.x;
    const int lane = tid & 63;
    const int wave = tid >> 6;
    const int wr   = wave >> 1, wc = wave & 1;
    const int quad = lane >> 4, lrow = lane & 15;
    const int bm   = blockIdx.x, bn = blockIdx.y, z = blockIdx.z;  // bm fastest

    const unsigned short* Az = A + (long)z * sAz;
    const unsigned short* Bz = B + (long)z * sBz;

    const unsigned short* gA[4];
    const unsigned short* gB1;
#pragma unroll
    for (int i = 0; i < 4; ++i) {
        const int l = tid + 512 * i;
        const int r = l >> 3;
        const int c = (l & 7) ^ (r & 7);
        gA[i] = Az + (long)(bm * 256 + r) * ldA + c * 8;
    }
    {
        const int r = tid >> 3;
        const int c = (tid & 7) ^ (r & 7);
        gB1 = Bz + (long)(bn * 64 + r) * ldB + c * 8;
    }

    f32x4 acc[4][2];
#pragma unroll
    for (int i = 0; i < 4; ++i)
#pragma unroll
        for (int j = 0; j < 2; ++j)
            acc[i][j] = f32x4{0.f, 0.f, 0.f, 0.f};

    const int fr = lrow & 7;
    const int ntiles = K >> 6;

    // prologue: stage tile0 into buf0
#pragma unroll
    for (int i = 0; i < 4; ++i) async16(gA[i], &smem[(tid + 512 * i) * 8]);
    async16(gB1, &smem[256 * 64 + tid * 8]);
#pragma unroll
    for (int i = 0; i < 4; ++i) gA[i] += 64;
    gB1 += 64;
    __syncthreads();   // drains vmcnt(0): tile0 visible

    for (int t = 0; t < ntiles; ++t) {
        const unsigned short* As = smem + (t & 1) * TILE_H;
        const unsigned short* Bs = As + 256 * 64;

        // issue next tile's loads into the other buffer (dead since the
        // barrier at end of tile t-1), then compute under them.
        if (t + 1 < ntiles) {
            unsigned short* nA = smem + ((t + 1) & 1) * TILE_H;
#pragma unroll
            for (int i = 0; i < 4; ++i) {
                async16(gA[i], &nA[(tid + 512 * i) * 8]);
                gA[i] += 64;
            }
            async16(gB1, &nA[256 * 64 + tid * 8]);
            gB1 += 64;
        }

#pragma unroll
        for (int ks = 0; ks < 2; ++ks) {
            const int pc = (((ks << 2) + quad) ^ fr) * 8;
            f16x8 af[4], bf[2];
#pragma unroll
            for (int mt = 0; mt < 4; ++mt)
                af[mt] = *(const f16x8*)&As[(wr * 64 + mt * 16 + lrow) * 64 + pc];
#pragma unroll
            for (int nt = 0; nt < 2; ++nt)
                bf[nt] = *(const f16x8*)&Bs[(wc * 32 + nt * 16 + lrow) * 64 + pc];
#pragma unroll
            for (int mt = 0; mt < 4; ++mt)
#pragma unroll
                for (int nt = 0; nt < 2; ++nt)
                    acc[mt][nt] = __builtin_amdgcn_mfma_f32_16x16x32_f16(
                        af[mt], bf[nt], acc[mt][nt], 0, 0, 0);
        }

        if (t + 1 < ntiles)
            __syncthreads();   // drain(t+1 loads) + all waves done reading buf
    }

    const int col_base = bn * 64 + wc * 32;
    const int row_base = bm * 256 + wr * 64;
    const long zC = (long)z * sCz;
#pragma unroll
    for (int mt = 0; mt < 4; ++mt)
#pragma unroll
        for (int nt = 0; nt < 2; ++nt)
#pragma unroll
            for (int r = 0; r < 4; ++r) {
                const int row = row_base + mt * 16 + quad * 4 + r;
                const int col = col_base + nt * 16 + lrow;
                C[zC + (long)row * ldC + col] = acc[mt][nt][r];
            }
}

// fused fp32 -> fp16 conversion: blocks [0,4096) -> x, [4096,5632) -> weights
__global__ __launch_bounds__(256)
void cvt_all(const float* __restrict__ x, const float* __restrict__ w0,
             const float* __restrict__ w1, const float* __restrict__ w2,
             unsigned short* __restrict__ xh, unsigned short* __restrict__ wh)
{
    const int bid = blockIdx.x;
    const float* s;
    unsigned short* d;
    long i;
    if (bid < 4096) {
        s = x; d = xh;
        i = ((long)bid * 256 + threadIdx.x) * 8;
    } else {
        const int wid = bid - 4096;          // [0,1536)
        const int w = wid >> 9;              // weight index
        s = (w == 0) ? w0 : (w == 1) ? w1 : w2;
        d = wh + (long)w * 1048576;
        i = ((long)(wid & 511) * 256 + threadIdx.x) * 8;
    }
    f32x4 a = *(const f32x4*)(s + i);
    f32x4 b = *(const f32x4*)(s + i + 4);
    union { unsigned short u[8]; f16x8 v; } t;
#pragma unroll
    for (int j = 0; j < 4; ++j) { t.u[j] = f2h(a[j]); t.u[4 + j] = f2h(b[j]); }
    *(f16x8*)(d + i) = t.v;
}

// in-place fp16 row softmax: row = 2048 fp16, one block per row.
__global__ __launch_bounds__(256)
void softmax16(unsigned short* __restrict__ sc)
{
    const long row = blockIdx.x;
    unsigned short* srow = sc + row * 2048;
    const int tid = threadIdx.x;

    union { u16x4 p[2]; unsigned short u[8]; } in;
    in.p[0] = *(const u16x4*)(srow + tid * 8);
    in.p[1] = *(const u16x4*)(srow + tid * 8 + 4);
    float v[8];
#pragma unroll
    for (int i = 0; i < 8; ++i) v[i] = h2f(in.u[i]);

    float m = v[0];
#pragma unroll
    for (int i = 1; i < 8; ++i) m = fmaxf(m, v[i]);
#pragma unroll
    for (int off = 32; off; off >>= 1) m = fmaxf(m, __shfl_xor(m, off));

    __shared__ float redm[4], reds[4];
    if ((tid & 63) == 0) redm[tid >> 6] = m;
    __syncthreads();
    m = fmaxf(fmaxf(redm[0], redm[1]), fmaxf(redm[2], redm[3]));

    float s = 0.f;
#pragma unroll
    for (int i = 0; i < 8; ++i) { v[i] = __expf(v[i] - m); s += v[i]; }
#pragma unroll
    for (int off = 32; off; off >>= 1) s += __shfl_xor(s, off);
    if ((tid & 63) == 0) reds[tid >> 6] = s;
    __syncthreads();
    s = reds[0] + reds[1] + reds[2] + reds[3];

    const float inv = 1.f / s;
    union { unsigned short u[8]; f16x8 w; } t;
#pragma unroll
    for (int i = 0; i < 8; ++i) t.u[i] = f2h(v[i] * inv);
    *(f16x8*)(srow + tid * 8) = t.w;
}

extern "C" void kernel_launch(void* const* d_in, const int* in_sizes, int n_in,
                              void* d_out, int out_size, void* d_ws, size_t ws_size,
                              hipStream_t stream)
{
    const float* x  = (const float*)d_in[0];
    const float* wq = (const float*)d_in[1];
    const float* wk = (const float*)d_in[2];
    const float* wv = (const float*)d_in[3];
    float* out = (float*)d_out;

    // batched: [sc fp16 33.5MB (aliases xh 16.8 | wh 6.3)] [q][k][vt] = 83.9MB
    // looped:  [xh|wh 23.1MB (per-batch sc fp16 8.4MB aliases xh)][q][k][vt]
    //          = 73.4MB
    char* base = (char*)d_ws;
    const bool batched = (ws_size >= 88080384UL);   // 84 MB

    unsigned short* xh = (unsigned short*)base;
    unsigned short* wh = (unsigned short*)(base + 16777216);
    unsigned short* sc = (unsigned short*)base;
    unsigned short* q  = (unsigned short*)(base + (batched ? 33554432 : 23068672));
    unsigned short* k  = q + 8388608;
    unsigned short* vt = k + 8388608;

    // 0) conversions (single dispatch)
    cvt_all<<<5632, 256, 0, stream>>>(x, wq, wk, wv, xh, wh);

    // 1) fused projections: M=8192 N=1024 K=1024; z=0,1 -> q,k; z=2 -> vt
    //    grid (32,8,3) = 768 blocks = 3/CU
    gemm512<0, 128><<<dim3(32, 8, 3), 512, 0, stream>>>(
        xh, wh, q, vt, 1024, 1024, 1024, 1024, 0L, 1048576L, 8388608L);

    if (batched) {
        // 2) scores fp16: M=N=2048 K=1024, z=batch; (8,16,4)=512 blocks
        gemm512<1, 128><<<dim3(8, 16, 4), 512, 0, stream>>>(
            q, k, sc, nullptr, 1024, 1024, 1024, 2048,
            2097152L, 2097152L, 4194304L);
        // 3) softmax in place (8192 rows, fp16->fp16)
        softmax16<<<8192, 256, 0, stream>>>(sc);
        // 4) out: M=2048 N=1024 K=2048; 256x64 tiles, (8,16,4)=512 blocks,
        //    double-buffered 2-phase (R9)
        gemm_out<<<dim3(8, 16, 4), 512, 0, stream>>>(
            sc, vt, out, 2048, 2048, 2048, 1024,
            4194304L, 2097152L, 2097152L);
    } else {
        for (int b = 0; b < 4; ++b) {
            gemm512<1, 128><<<dim3(8, 16, 1), 512, 0, stream>>>(
                q + (long)b * 2097152, k + (long)b * 2097152, sc, nullptr,
                1024, 1024, 1024, 2048, 0L, 0L, 0L);
            softmax16<<<2048, 256, 0, stream>>>(sc);
            gemm_out<<<dim3(8, 16, 1), 512, 0, stream>>>(
                sc, vt + (long)b * 2097152, out + (long)b * 2097152,
                2048, 2048, 2048, 1024, 0L, 0L, 0L);
        }
    }
}